// Round 1
// baseline (139.120 us; speedup 1.0000x reference)
//
#include <hip/hip_runtime.h>
#include <hip/hip_bf16.h>

#define NN 100000
#define CC 128
#define KK 32
#define BB 64
#define PS 16          // pool slices per graph

typedef __bf16 bf16x8 __attribute__((ext_vector_type(8)));
typedef float  f32x4  __attribute__((ext_vector_type(4)));

// Native gfx950 bf16 convert (RNE via v_cvt_pk_bf16_f32 — compiler lowers casts)
__device__ __forceinline__ unsigned short f2bf(float v) {
    union { __bf16 h; unsigned short s; } u;
    u.h = (__bf16)v;
    return u.s;
}
__device__ __forceinline__ float bf2f(unsigned short h) {
    union { unsigned u; float f; } a; a.u = ((unsigned)h) << 16;
    return a.f;
}
// unpack 8 uints (hi|lo<<16) -> two bf16x8 via v_perm_b32 (8 VALU total)
__device__ __forceinline__ void unpack_hilo(uint4 a, uint4 b,
                                            bf16x8& hi8, bf16x8& lo8) {
    union { unsigned u[4]; bf16x8 v; } H, L;
    H.u[0] = __builtin_amdgcn_perm(a.y, a.x, 0x05040100u);
    H.u[1] = __builtin_amdgcn_perm(a.w, a.z, 0x05040100u);
    H.u[2] = __builtin_amdgcn_perm(b.y, b.x, 0x05040100u);
    H.u[3] = __builtin_amdgcn_perm(b.w, b.z, 0x05040100u);
    L.u[0] = __builtin_amdgcn_perm(a.y, a.x, 0x07060302u);
    L.u[1] = __builtin_amdgcn_perm(a.w, a.z, 0x07060302u);
    L.u[2] = __builtin_amdgcn_perm(b.y, b.x, 0x07060302u);
    L.u[3] = __builtin_amdgcn_perm(b.w, b.z, 0x07060302u);
    hi8 = H.v; lo8 = L.v;
}

__device__ __forceinline__ void atomAddF(float* p, float v) {
#if defined(__gfx950__) || defined(__gfx942__) || defined(__gfx90a__)
    unsafeAtomicAdd(p, v);           // native global_atomic_add_f32
#else
    atomicAdd(p, v);
#endif
}

// ---------------------------------------------------------------------------
// Kernel 1 (prep): bounds + W1 & W2 -> bf16 hi/lo MFMA B-fragments + zero out.
// Grid: 64 blocks x 256 = 16384 threads.
// ---------------------------------------------------------------------------
__global__ __launch_bounds__(256) void hp_prep(const int* __restrict__ batch,
                                               const float* __restrict__ W1,
                                               const float* __restrict__ W2,
                                               int* __restrict__ bounds,
                                               unsigned short* __restrict__ w1f,
                                               unsigned short* __restrict__ w2f,
                                               float* __restrict__ out_zero) {
    if (blockIdx.x == 0 && threadIdx.x <= BB) {
        const int b = threadIdx.x;
        int lo = 0, hi = NN;
        while (lo < hi) {
            const int mid = (lo + hi) >> 1;
            if (batch[mid] < b) lo = mid + 1; else hi = mid;
        }
        bounds[b] = lo;
    }
    const int t = blockIdx.x * 256 + threadIdx.x;
    {   // W1 fragments: 16384 elements, one per thread
        const int idx  = t;
        const int j    = idx & 7;
        const int lane = (idx >> 3) & 63;
        const int nt   = (idx >> 9) & 7;
        const int kt   = idx >> 12;
        const int k = kt * 32 + (lane >> 4) * 8 + j;
        const int n = nt * 16 + (lane & 15);
        const float w = W1[k * CC + n];
        const unsigned short h = f2bf(w);
        w1f[idx]         = h;
        w1f[16384 + idx] = f2bf(w - bf2f(h));
    }
    if (t < 4096) {  // W2 fragments
        const int idx  = t;
        const int j    = idx & 7;
        const int lane = (idx >> 3) & 63;
        const int nt   = (idx >> 9) & 1;
        const int kt   = idx >> 10;
        const int k = kt * 32 + (lane >> 4) * 8 + j;
        const int n = nt * 16 + (lane & 15);
        const float w = W2[k * KK + n];
        const unsigned short h = f2bf(w);
        w2f[idx]        = h;
        w2f[4096 + idx] = f2bf(w - bf2f(h));
    }
    // zero the pooled output tile [B,K,C] (pool accumulates atomically)
    const float4 z = make_float4(0.f, 0.f, 0.f, 0.f);
    #pragma unroll
    for (int i = t; i < BB * KK * CC / 4; i += 16384)
        *(float4*)(out_zero + (size_t)i * 4) = z;
}

// ---------------------------------------------------------------------------
// Kernel 2: MLP (both layers split-bf16 MFMA) + softmax; also emits pool
// operand fragments:
//   xb[chunk 3125][ct 8][lane 64][j 8] = bf16 x[ch*32+(lane>>4)*8+j][ct*16+(lane&15)]
//   sb[chunk 3125][mt 2][lane 64][j 8] = bf16 s[ch*32+(lane>>4)*8+j][mt*16+(lane&15)]
// Block = 32 nodes = one chunk (3125 blocks), 256 threads, 4 waves.
// ---------------------------------------------------------------------------
__global__ __launch_bounds__(256, 6) void hp_mlp(
    const float* __restrict__ x,
    const unsigned short* __restrict__ w1f,
    const unsigned short* __restrict__ w2f,
    const float* __restrict__ b1,
    const float* __restrict__ b2,
    float* __restrict__ s_out,
    unsigned short* __restrict__ xb,
    unsigned short* __restrict__ sb)
{
    __shared__ __align__(16) char uni[16896];     // xa (16384 B) / hs16 (16896 B)
    __shared__ float lgT[32][36];                 // [node][k] logits, then s
    __shared__ float redm[4][32];
    __shared__ float reds[4][32];

    unsigned short* xa   = (unsigned short*)uni;  // [split][q=mt*4+kt][lane][8]
    unsigned int*   hs16 = (unsigned int*)uni;    // [node][132]: hi | lo<<16

    const int t    = threadIdx.x;
    const int wave = __builtin_amdgcn_readfirstlane(t >> 6);
    const int lane = t & 63;
    const int base = blockIdx.x * 32;

    // ---- stage x -> bf16 hi/lo A-frags (thread does mt = 0,1; kt = wave) ----
    #pragma unroll
    for (int mt = 0; mt < 2; ++mt) {
        const int q  = mt * 4 + wave;
        const int n  = base + mt * 16 + (lane & 15);
        const int ck = wave * 32 + (lane >> 4) * 8;
        const float4 va = *(const float4*)(x + (size_t)n * CC + ck);
        const float4 vb = *(const float4*)(x + (size_t)n * CC + ck + 4);
        const float v[8] = {va.x, va.y, va.z, va.w, vb.x, vb.y, vb.z, vb.w};
        union { unsigned short s[8]; uint4 u; } H, L;
        #pragma unroll
        for (int j = 0; j < 8; ++j) {
            H.s[j] = f2bf(v[j]);
            L.s[j] = f2bf(v[j] - bf2f(H.s[j]));
        }
        unsigned short* d0 = xa + (q * 64 + lane) * 8;
        *(uint4*)(d0)        = H.u;
        *(uint4*)(d0 + 4096) = L.u;
    }

    // ---- emit xb pool B-frags (x re-read is L1/L2-hot; quarter-wave 64B) ----
    #pragma unroll
    for (int cc = 0; cc < 2; ++cc) {
        const int ct = wave * 2 + cc;
        const int c  = ct * 16 + (lane & 15);
        const int nb = base + (lane >> 4) * 8;
        union { unsigned short s[8]; uint4 u; } Hb;
        #pragma unroll
        for (int j = 0; j < 8; ++j)
            Hb.s[j] = f2bf(x[(size_t)(nb + j) * CC + c]);
        unsigned short* dp = xb + ((size_t)(blockIdx.x * 8 + ct) * 64 + lane) * 8;
        *(uint4*)dp = Hb.u;
    }
    __syncthreads();

    // ---- phase 1: MFMA; wave owns n-tiles 2w, 2w+1 ----
    f32x4 acc[2][2];
    #pragma unroll
    for (int mt = 0; mt < 2; ++mt)
        #pragma unroll
        for (int nl = 0; nl < 2; ++nl)
            acc[mt][nl] = (f32x4){0.f, 0.f, 0.f, 0.f};

    #pragma unroll
    for (int kt = 0; kt < 4; ++kt) {
        bf16x8 ah[2], al[2];
        #pragma unroll
        for (int mt = 0; mt < 2; ++mt) {
            ah[mt] = *(const bf16x8*)(xa + ((mt * 4 + kt) * 64 + lane) * 8);
            al[mt] = *(const bf16x8*)(xa + 4096 + ((mt * 4 + kt) * 64 + lane) * 8);
        }
        #pragma unroll
        for (int nl = 0; nl < 2; ++nl) {
            const int nt = 2 * wave + nl;
            const bf16x8 wh = *(const bf16x8*)(w1f + ((kt * 8 + nt) * 64 + lane) * 8);
            const bf16x8 wl = *(const bf16x8*)(w1f + 16384 + ((kt * 8 + nt) * 64 + lane) * 8);
            #pragma unroll
            for (int mt = 0; mt < 2; ++mt) {
                acc[mt][nl] = __builtin_amdgcn_mfma_f32_16x16x32_bf16(ah[mt], wh, acc[mt][nl], 0, 0, 0);
                acc[mt][nl] = __builtin_amdgcn_mfma_f32_16x16x32_bf16(al[mt], wh, acc[mt][nl], 0, 0, 0);
                acc[mt][nl] = __builtin_amdgcn_mfma_f32_16x16x32_bf16(ah[mt], wl, acc[mt][nl], 0, 0, 0);
            }
        }
    }
    __syncthreads();                               // xa dead; hs16 overlays

    // ---- epilogue: bias+relu, pack hi|lo<<16 -> hs16[node][132] ----
    #pragma unroll
    for (int nl = 0; nl < 2; ++nl) {
        const int c = (2 * wave + nl) * 16 + (lane & 15);
        const float bv = b1[c];
        #pragma unroll
        for (int mt = 0; mt < 2; ++mt)
            #pragma unroll
            for (int r = 0; r < 4; ++r) {
                const int node = mt * 16 + (lane >> 4) * 4 + r;
                const float h = fmaxf(acc[mt][nl][r] + bv, 0.f);
                const unsigned short hi = f2bf(h);
                const unsigned short lo = f2bf(h - bf2f(hi));
                hs16[node * 132 + c] = (unsigned)hi | ((unsigned)lo << 16);
            }
    }
    __syncthreads();

    // ---- phase 2: logits via MFMA; wave = (mt2 = w&1, nt2 = w>>1) ----
    {
        const int mt2 = wave & 1, nt2 = wave >> 1;
        f32x4 dacc = (f32x4){0.f, 0.f, 0.f, 0.f};
        #pragma unroll
        for (int kt = 0; kt < 4; ++kt) {
            const unsigned* hp = hs16 + (mt2 * 16 + (lane & 15)) * 132
                                      + kt * 32 + (lane >> 4) * 8;
            const uint4 u0 = *(const uint4*)hp;
            const uint4 u1 = *(const uint4*)(hp + 4);
            bf16x8 ah, al;
            unpack_hilo(u0, u1, ah, al);
            const bf16x8 wh = *(const bf16x8*)(w2f + ((kt * 2 + nt2) * 64 + lane) * 8);
            const bf16x8 wl = *(const bf16x8*)(w2f + 4096 + ((kt * 2 + nt2) * 64 + lane) * 8);
            dacc = __builtin_amdgcn_mfma_f32_16x16x32_bf16(ah, wh, dacc, 0, 0, 0);
            dacc = __builtin_amdgcn_mfma_f32_16x16x32_bf16(al, wh, dacc, 0, 0, 0);
            dacc = __builtin_amdgcn_mfma_f32_16x16x32_bf16(ah, wl, dacc, 0, 0, 0);
        }
        const int kcol = nt2 * 16 + (lane & 15);
        #pragma unroll
        for (int r = 0; r < 4; ++r) {
            const int node = mt2 * 16 + (lane >> 4) * 4 + r;
            lgT[node][kcol] = dacc[r];
        }
    }
    __syncthreads();

    // ---- phase 3: softmax (2-round LDS combine) ----
    const int node = lane & 31;
    const int koff = ((lane >> 5) << 4) + wave * 4;
    const float4 bv2 = *(const float4*)(b2 + koff);
    const float4 lv  = *(const float4*)&lgT[node][koff];
    float lg[4] = {lv.x + bv2.x, lv.y + bv2.y, lv.z + bv2.z, lv.w + bv2.w};

    float m = fmaxf(fmaxf(lg[0], lg[1]), fmaxf(lg[2], lg[3]));
    m = fmaxf(m, __shfl_xor(m, 32));
    if (lane < 32) redm[wave][lane] = m;
    __syncthreads();
    const float M = fmaxf(fmaxf(redm[0][node], redm[1][node]),
                          fmaxf(redm[2][node], redm[3][node]));
    const float e0 = __expf(lg[0] - M);
    const float e1 = __expf(lg[1] - M);
    const float e2 = __expf(lg[2] - M);
    const float e3 = __expf(lg[3] - M);
    float sp = (e0 + e1) + (e2 + e3);
    sp += __shfl_xor(sp, 32);
    if (lane < 32) reds[wave][lane] = sp;
    __syncthreads();
    const float S = (reds[0][node] + reds[1][node]) + (reds[2][node] + reds[3][node]);
    const float inv = 1.f / S;
    const float4 s4 = make_float4(e0 * inv, e1 * inv, e2 * inv, e3 * inv);
    *(float4*)(s_out + (size_t)(base + node) * KK + koff) = s4;
    *(float4*)&lgT[node][koff] = s4;               // normalized s for sb pack
    __syncthreads();

    // ---- emit sb pool A-frags (waves 0,1: mt = wave) ----
    if (wave < 2) {
        const int k  = wave * 16 + (lane & 15);
        const int r0 = (lane >> 4) * 8;
        union { unsigned short s[8]; uint4 u; } V;
        #pragma unroll
        for (int j = 0; j < 8; ++j)
            V.s[j] = f2bf(lgT[r0 + j][k]);
        unsigned short* dp = sb + ((size_t)(blockIdx.x * 2 + wave) * 64 + lane) * 8;
        *(uint4*)dp = V.u;
    }
}

// ---------------------------------------------------------------------------
// Kernel 3: pooling via MFMA on pre-built frags. Block = (graph b, slice p);
// 4 waves: wave = (mt = w&1, chalf = w>>1). Per 32-node chunk per wave:
// 1 sb A-frag (boundary-masked) + 4 xb B-frags + 4 MFMA. Zero LDS/barriers.
// Epilogue: native fp32 atomics straight into out[b] (pre-zeroed by hp_prep)
// — removes the part round-trip and the reduce dispatch entirely.
// ---------------------------------------------------------------------------
__global__ __launch_bounds__(256) void hp_pool(
    const unsigned short* __restrict__ xb,
    const unsigned short* __restrict__ sb,
    const int* __restrict__ bounds,
    float* __restrict__ out)
{
    const int b = blockIdx.x / PS;
    const int p = blockIdx.x - b * PS;
    const int wave = __builtin_amdgcn_readfirstlane(threadIdx.x >> 6);
    const int lane = threadIdx.x & 63;

    const int gs = bounds[b], ge = bounds[b + 1];
    const int c0g = gs >> 5;
    const int cnt = ((ge + 31) >> 5) - c0g;
    const int ch0 = c0g + (cnt * p) / PS;
    const int ch1 = c0g + (cnt * (p + 1)) / PS;

    const int mt    = wave & 1;
    const int chalf = wave >> 1;
    const int nrow  = (lane >> 4) * 8;

    f32x4 acc[4];
    #pragma unroll
    for (int i = 0; i < 4; ++i) acc[i] = (f32x4){0.f, 0.f, 0.f, 0.f};

    for (int ch = ch0; ch < ch1; ++ch) {
        union { uint4 u; unsigned short s[8]; bf16x8 v; } A;
        A.u = *(const uint4*)(sb + ((size_t)(ch * 2 + mt) * 64 + lane) * 8);
        const int nb = ch * 32 + nrow;
        #pragma unroll
        for (int j = 0; j < 8; ++j)
            if (nb + j < gs || nb + j >= ge) A.s[j] = 0;   // mask other graphs
        #pragma unroll
        for (int i = 0; i < 4; ++i) {
            const int ct = chalf * 4 + i;
            const bf16x8 Bv = *(const bf16x8*)(xb + ((size_t)(ch * 8 + ct) * 64 + lane) * 8);
            acc[i] = __builtin_amdgcn_mfma_f32_16x16x32_bf16(A.v, Bv, acc[i], 0, 0, 0);
        }
    }

    float* op = out + (size_t)b * KK * CC;
    #pragma unroll
    for (int i = 0; i < 4; ++i) {
        const int c = (chalf * 4 + i) * 16 + (lane & 15);
        #pragma unroll
        for (int r = 0; r < 4; ++r) {
            const int k = mt * 16 + (lane >> 4) * 4 + r;
            atomAddF(op + k * CC + c, acc[i][r]);
        }
    }
}

// ---------------------------------------------------------------------------
extern "C" void kernel_launch(void* const* d_in, const int* in_sizes, int n_in,
                              void* d_out, int out_size, void* d_ws, size_t ws_size,
                              hipStream_t stream) {
    const float* x     = (const float*)d_in[0];
    const int*   batch = (const int*)d_in[1];
    const float* W1    = (const float*)d_in[2];
    const float* b1    = (const float*)d_in[3];
    const float* W2    = (const float*)d_in[4];
    const float* b2    = (const float*)d_in[5];

    float* out = (float*)d_out;                    // [B,K,C] = 262144 floats
    float* s   = out + (size_t)BB * KK * CC;       // [N,K]   = 3200000 floats

    char* ws = (char*)d_ws;
    int*            bounds = (int*)ws;                          // 512 B
    unsigned short* w1f    = (unsigned short*)(ws + 1024);      // 64 KB
    unsigned short* w2f    = (unsigned short*)(ws + 66560);     // 16 KB
    unsigned short* xb     = (unsigned short*)(ws + 82944);     // 25.6 MB
    unsigned short* sb     = (unsigned short*)(ws + 82944 + 25600000);      // 6.4 MB

    hp_prep<<<64, 256, 0, stream>>>(batch, W1, W2, bounds, w1f, w2f, out);
    hp_mlp<<<NN / 32, 256, 0, stream>>>(x, w1f, w2f, b1, b2, s, xb, sb);
    hp_pool<<<BB * PS, 256, 0, stream>>>(xb, sb, bounds, out);
}

// Round 2
// 132.877 us; speedup vs baseline: 1.0470x; 1.0470x over previous
//
#include <hip/hip_runtime.h>
#include <hip/hip_bf16.h>

#define NN 100000
#define CC 128
#define KK 32
#define BB 64
#define CH 4                // chunks (of 32 nodes) per fused block
#define NCHUNK (NN / 32)    // 3125

typedef __bf16 bf16x8 __attribute__((ext_vector_type(8)));
typedef float  f32x4  __attribute__((ext_vector_type(4)));

__device__ __forceinline__ unsigned short f2bf(float v) {
    union { __bf16 h; unsigned short s; } u;
    u.h = (__bf16)v;                     // native RNE cvt on gfx950
    return u.s;
}
__device__ __forceinline__ float bf2f(unsigned short h) {
    union { unsigned u; float f; } a; a.u = ((unsigned)h) << 16;
    return a.f;
}
// unpack 8 uints (hi|lo<<16) -> two bf16x8 via v_perm_b32
__device__ __forceinline__ void unpack_hilo(uint4 a, uint4 b,
                                            bf16x8& hi8, bf16x8& lo8) {
    union { unsigned u[4]; bf16x8 v; } H, L;
    H.u[0] = __builtin_amdgcn_perm(a.y, a.x, 0x05040100u);
    H.u[1] = __builtin_amdgcn_perm(a.w, a.z, 0x05040100u);
    H.u[2] = __builtin_amdgcn_perm(b.y, b.x, 0x05040100u);
    H.u[3] = __builtin_amdgcn_perm(b.w, b.z, 0x05040100u);
    L.u[0] = __builtin_amdgcn_perm(a.y, a.x, 0x07060302u);
    L.u[1] = __builtin_amdgcn_perm(a.w, a.z, 0x07060302u);
    L.u[2] = __builtin_amdgcn_perm(b.y, b.x, 0x07060302u);
    L.u[3] = __builtin_amdgcn_perm(b.w, b.z, 0x07060302u);
    hi8 = H.v; lo8 = L.v;
}

__device__ __forceinline__ void atomAddF(float* p, float v) {
#if defined(__gfx950__) || defined(__gfx942__) || defined(__gfx90a__)
    unsafeAtomicAdd(p, v);               // native global_atomic_add_f32
#else
    atomicAdd(p, v);
#endif
}

// ---------------------------------------------------------------------------
// Kernel 1 (prep): W1 & W2 -> bf16 hi/lo MFMA B-fragments + zero out tile.
// ---------------------------------------------------------------------------
__global__ __launch_bounds__(256) void hp_prep(const float* __restrict__ W1,
                                               const float* __restrict__ W2,
                                               unsigned short* __restrict__ w1f,
                                               unsigned short* __restrict__ w2f,
                                               float* __restrict__ out_zero) {
    const int t = blockIdx.x * 256 + threadIdx.x;
    {   // W1 fragments: 16384 elements, one per thread
        const int idx  = t;
        const int j    = idx & 7;
        const int lane = (idx >> 3) & 63;
        const int nt   = (idx >> 9) & 7;
        const int kt   = idx >> 12;
        const int k = kt * 32 + (lane >> 4) * 8 + j;
        const int n = nt * 16 + (lane & 15);
        const float w = W1[k * CC + n];
        const unsigned short h = f2bf(w);
        w1f[idx]         = h;
        w1f[16384 + idx] = f2bf(w - bf2f(h));
    }
    if (t < 4096) {  // W2 fragments
        const int idx  = t;
        const int j    = idx & 7;
        const int lane = (idx >> 3) & 63;
        const int nt   = (idx >> 9) & 1;
        const int kt   = idx >> 10;
        const int k = kt * 32 + (lane >> 4) * 8 + j;
        const int n = nt * 16 + (lane & 15);
        const float w = W2[k * KK + n];
        const unsigned short h = f2bf(w);
        w2f[idx]        = h;
        w2f[4096 + idx] = f2bf(w - bf2f(h));
    }
    // zero the pooled output tile [B,K,C] (fused kernel accumulates atomically)
    const float4 z = make_float4(0.f, 0.f, 0.f, 0.f);
    for (int i = t; i < BB * KK * CC / 4; i += 16384)
        *(float4*)(out_zero + (size_t)i * 4) = z;
}

// ---------------------------------------------------------------------------
// Kernel 2 (fused): per block, CH consecutive 32-node chunks.
// Per chunk: MLP layer1 (split-bf16 MFMA) -> ReLU -> layer2 -> softmax -> s_out,
// then pooling MFMAs accumulate s^T x into persistent per-wave registers.
// Graph boundaries handled by batch[]-equality masking of the s A-fragment;
// flush to out[g] via native fp32 atomics whenever the graph id advances.
// Wave roles (pool): mt = wave&1 (k half), chalf = wave>>1 (c half).
// ---------------------------------------------------------------------------
__global__ __launch_bounds__(256, 3) void hp_fused(
    const float* __restrict__ x,
    const unsigned short* __restrict__ w1f,
    const unsigned short* __restrict__ w2f,
    const float* __restrict__ b1,
    const float* __restrict__ b2,
    const int* __restrict__ batch,
    float* __restrict__ s_out,
    float* __restrict__ out)
{
    __shared__ __align__(16) char uni[16896];         // xa (16384 B) / hs16 (16896 B)
    __shared__ __align__(16) unsigned short xbL[8 * 64 * 8];   // 8 KB pool B-frags
    __shared__ float lgT[32][36];                     // [node][k] logits, then s
    __shared__ float redm[4][32];
    __shared__ float reds[4][32];

    unsigned short* xa   = (unsigned short*)uni;      // [split][q=mt*4+kt][lane][8]
    unsigned int*   hs16 = (unsigned int*)uni;        // [node][132]: hi | lo<<16

    const int t    = threadIdx.x;
    const int wave = __builtin_amdgcn_readfirstlane(t >> 6);
    const int lane = t & 63;

    const int pmt   = wave & 1;                       // pool: k-half
    const int chalf = wave >> 1;                      // pool: c-half
    const int nrow  = (lane >> 4) * 8;                // pool: first node row of lane

    f32x4 pacc[4];
    #pragma unroll
    for (int i = 0; i < 4; ++i) pacc[i] = (f32x4){0.f, 0.f, 0.f, 0.f};

    int cg = __builtin_amdgcn_readfirstlane(batch[blockIdx.x * (CH * 32)]);

    // flush current accumulator into out[g]
    auto flush = [&](int g) {
        float* op = out + (size_t)g * KK * CC;
        #pragma unroll
        for (int i = 0; i < 4; ++i) {
            const int c = (chalf * 4 + i) * 16 + (lane & 15);
            #pragma unroll
            for (int r = 0; r < 4; ++r) {
                const int k = pmt * 16 + (lane >> 4) * 4 + r;
                atomAddF(op + k * CC + c, pacc[i][r]);
            }
            pacc[i] = (f32x4){0.f, 0.f, 0.f, 0.f};
        }
    };

    #pragma unroll 1
    for (int ch = 0; ch < CH; ++ch) {
        const int chunk = blockIdx.x * CH + ch;
        if (chunk >= NCHUNK) break;
        const int base = chunk * 32;

        __syncthreads();   // prior chunk's pool reads of xbL/lgT done before overwrite

        // ---- stage x -> bf16 hi/lo A-frags (thread does mt = 0,1; kt = wave) ----
        #pragma unroll
        for (int mt = 0; mt < 2; ++mt) {
            const int q  = mt * 4 + wave;
            const int n  = base + mt * 16 + (lane & 15);
            const int ck = wave * 32 + (lane >> 4) * 8;
            const float4 va = *(const float4*)(x + (size_t)n * CC + ck);
            const float4 vb = *(const float4*)(x + (size_t)n * CC + ck + 4);
            const float v[8] = {va.x, va.y, va.z, va.w, vb.x, vb.y, vb.z, vb.w};
            union { unsigned short s[8]; uint4 u; } H, L;
            #pragma unroll
            for (int j = 0; j < 8; ++j) {
                H.s[j] = f2bf(v[j]);
                L.s[j] = f2bf(v[j] - bf2f(H.s[j]));
            }
            unsigned short* d0 = xa + (q * 64 + lane) * 8;
            *(uint4*)(d0)        = H.u;
            *(uint4*)(d0 + 4096) = L.u;
        }

        // ---- emit pool B-frags into LDS (x re-read is L1-hot) ----
        #pragma unroll
        for (int cc = 0; cc < 2; ++cc) {
            const int ct = wave * 2 + cc;
            const int c  = ct * 16 + (lane & 15);
            const int nb = base + nrow;
            union { unsigned short s[8]; uint4 u; } Hb;
            #pragma unroll
            for (int j = 0; j < 8; ++j)
                Hb.s[j] = f2bf(x[(size_t)(nb + j) * CC + c]);
            *(uint4*)(xbL + ((size_t)ct * 64 + lane) * 8) = Hb.u;
        }
        __syncthreads();

        // ---- phase 1: layer-1 MFMA; wave owns n-tiles 2w, 2w+1 ----
        f32x4 acc[2][2];
        #pragma unroll
        for (int mt = 0; mt < 2; ++mt)
            #pragma unroll
            for (int nl = 0; nl < 2; ++nl)
                acc[mt][nl] = (f32x4){0.f, 0.f, 0.f, 0.f};

        #pragma unroll
        for (int kt = 0; kt < 4; ++kt) {
            bf16x8 ah[2], al[2];
            #pragma unroll
            for (int mt = 0; mt < 2; ++mt) {
                ah[mt] = *(const bf16x8*)(xa + ((mt * 4 + kt) * 64 + lane) * 8);
                al[mt] = *(const bf16x8*)(xa + 4096 + ((mt * 4 + kt) * 64 + lane) * 8);
            }
            #pragma unroll
            for (int nl = 0; nl < 2; ++nl) {
                const int nt = 2 * wave + nl;
                const bf16x8 wh = *(const bf16x8*)(w1f + ((kt * 8 + nt) * 64 + lane) * 8);
                const bf16x8 wl = *(const bf16x8*)(w1f + 16384 + ((kt * 8 + nt) * 64 + lane) * 8);
                #pragma unroll
                for (int mt = 0; mt < 2; ++mt) {
                    acc[mt][nl] = __builtin_amdgcn_mfma_f32_16x16x32_bf16(ah[mt], wh, acc[mt][nl], 0, 0, 0);
                    acc[mt][nl] = __builtin_amdgcn_mfma_f32_16x16x32_bf16(al[mt], wh, acc[mt][nl], 0, 0, 0);
                    acc[mt][nl] = __builtin_amdgcn_mfma_f32_16x16x32_bf16(ah[mt], wl, acc[mt][nl], 0, 0, 0);
                }
            }
        }
        __syncthreads();                               // xa dead; hs16 overlays

        // ---- epilogue: bias+relu, pack hi|lo<<16 -> hs16[node][132] ----
        #pragma unroll
        for (int nl = 0; nl < 2; ++nl) {
            const int c = (2 * wave + nl) * 16 + (lane & 15);
            const float bv = b1[c];
            #pragma unroll
            for (int mt = 0; mt < 2; ++mt)
                #pragma unroll
                for (int r = 0; r < 4; ++r) {
                    const int node = mt * 16 + (lane >> 4) * 4 + r;
                    const float h = fmaxf(acc[mt][nl][r] + bv, 0.f);
                    const unsigned short hi = f2bf(h);
                    const unsigned short lo = f2bf(h - bf2f(hi));
                    hs16[node * 132 + c] = (unsigned)hi | ((unsigned)lo << 16);
                }
        }
        __syncthreads();

        // ---- phase 2: logits via MFMA; wave = (mt2 = w&1, nt2 = w>>1) ----
        {
            const int mt2 = wave & 1, nt2 = wave >> 1;
            f32x4 dacc = (f32x4){0.f, 0.f, 0.f, 0.f};
            #pragma unroll
            for (int kt = 0; kt < 4; ++kt) {
                const unsigned* hp = hs16 + (mt2 * 16 + (lane & 15)) * 132
                                          + kt * 32 + (lane >> 4) * 8;
                const uint4 u0 = *(const uint4*)hp;
                const uint4 u1 = *(const uint4*)(hp + 4);
                bf16x8 ah, al;
                unpack_hilo(u0, u1, ah, al);
                const bf16x8 wh = *(const bf16x8*)(w2f + ((kt * 2 + nt2) * 64 + lane) * 8);
                const bf16x8 wl = *(const bf16x8*)(w2f + 4096 + ((kt * 2 + nt2) * 64 + lane) * 8);
                dacc = __builtin_amdgcn_mfma_f32_16x16x32_bf16(ah, wh, dacc, 0, 0, 0);
                dacc = __builtin_amdgcn_mfma_f32_16x16x32_bf16(al, wh, dacc, 0, 0, 0);
                dacc = __builtin_amdgcn_mfma_f32_16x16x32_bf16(ah, wl, dacc, 0, 0, 0);
            }
            const int kcol = nt2 * 16 + (lane & 15);
            #pragma unroll
            for (int r = 0; r < 4; ++r) {
                const int node = mt2 * 16 + (lane >> 4) * 4 + r;
                lgT[node][kcol] = dacc[r];
            }
        }
        __syncthreads();

        // ---- phase 3: softmax (2-round LDS combine) ----
        {
            const int node = lane & 31;
            const int koff = ((lane >> 5) << 4) + wave * 4;
            const float4 bv2 = *(const float4*)(b2 + koff);
            const float4 lv  = *(const float4*)&lgT[node][koff];
            float lg[4] = {lv.x + bv2.x, lv.y + bv2.y, lv.z + bv2.z, lv.w + bv2.w};

            float m = fmaxf(fmaxf(lg[0], lg[1]), fmaxf(lg[2], lg[3]));
            m = fmaxf(m, __shfl_xor(m, 32));
            if (lane < 32) redm[wave][lane] = m;
            __syncthreads();
            const float M = fmaxf(fmaxf(redm[0][node], redm[1][node]),
                                  fmaxf(redm[2][node], redm[3][node]));
            const float e0 = __expf(lg[0] - M);
            const float e1 = __expf(lg[1] - M);
            const float e2 = __expf(lg[2] - M);
            const float e3 = __expf(lg[3] - M);
            float sp = (e0 + e1) + (e2 + e3);
            sp += __shfl_xor(sp, 32);
            if (lane < 32) reds[wave][lane] = sp;
            __syncthreads();
            const float S = (reds[0][node] + reds[1][node]) + (reds[2][node] + reds[3][node]);
            const float inv = 1.f / S;
            const float4 s4 = make_float4(e0 * inv, e1 * inv, e2 * inv, e3 * inv);
            *(float4*)(s_out + (size_t)(base + node) * KK + koff) = s4;
            *(float4*)&lgT[node][koff] = s4;           // normalized s for pool
        }
        __syncthreads();

        // ---- pool phase: s^T x accumulate (per-wave quadrant, no barriers) ----
        {
            // A-frag: s[k = pmt*16+(lane&15)] for nodes nrow..nrow+7
            union { unsigned short s[8]; bf16x8 v; } A;
            const int kA = pmt * 16 + (lane & 15);
            #pragma unroll
            for (int j = 0; j < 8; ++j)
                A.s[j] = f2bf(lgT[nrow + j][kA]);
            // B-frags from LDS
            bf16x8 Bv[4];
            #pragma unroll
            for (int i = 0; i < 4; ++i)
                Bv[i] = *(const bf16x8*)(xbL + ((size_t)(chalf * 4 + i) * 64 + lane) * 8);

            const int gl0 = __builtin_amdgcn_readfirstlane(batch[base]);
            const int gh  = __builtin_amdgcn_readfirstlane(batch[base + 31]);

            if (gl0 == cg && gh == cg) {
                // fast path: whole chunk in current graph
                #pragma unroll
                for (int i = 0; i < 4; ++i)
                    pacc[i] = __builtin_amdgcn_mfma_f32_16x16x32_bf16(A.v, Bv[i], pacc[i], 0, 0, 0);
            } else {
                int bt[8];
                #pragma unroll
                for (int j = 0; j < 8; ++j) bt[j] = batch[base + nrow + j];
                while (cg < gh) {
                    union { unsigned short s[8]; bf16x8 v; } Am;
                    #pragma unroll
                    for (int j = 0; j < 8; ++j)
                        Am.s[j] = (bt[j] == cg) ? A.s[j] : (unsigned short)0;
                    #pragma unroll
                    for (int i = 0; i < 4; ++i)
                        pacc[i] = __builtin_amdgcn_mfma_f32_16x16x32_bf16(Am.v, Bv[i], pacc[i], 0, 0, 0);
                    flush(cg);
                    ++cg;
                }
                // remaining nodes of graph cg (== gh)
                union { unsigned short s[8]; bf16x8 v; } Am;
                #pragma unroll
                for (int j = 0; j < 8; ++j)
                    Am.s[j] = (bt[j] == cg) ? A.s[j] : (unsigned short)0;
                #pragma unroll
                for (int i = 0; i < 4; ++i)
                    pacc[i] = __builtin_amdgcn_mfma_f32_16x16x32_bf16(Am.v, Bv[i], pacc[i], 0, 0, 0);
            }
        }
    }

    flush(cg);   // pending accumulation
}

// ---------------------------------------------------------------------------
extern "C" void kernel_launch(void* const* d_in, const int* in_sizes, int n_in,
                              void* d_out, int out_size, void* d_ws, size_t ws_size,
                              hipStream_t stream) {
    const float* x     = (const float*)d_in[0];
    const int*   batch = (const int*)d_in[1];
    const float* W1    = (const float*)d_in[2];
    const float* b1    = (const float*)d_in[3];
    const float* W2    = (const float*)d_in[4];
    const float* b2    = (const float*)d_in[5];

    float* out = (float*)d_out;                    // [B,K,C] = 262144 floats
    float* s   = out + (size_t)BB * KK * CC;       // [N,K]   = 3200000 floats

    char* ws = (char*)d_ws;
    unsigned short* w1f = (unsigned short*)ws;                  // 64 KB
    unsigned short* w2f = (unsigned short*)(ws + 65536);        // 16 KB

    hp_prep<<<64, 256, 0, stream>>>(W1, W2, w1f, w2f, out);
    const int nblk = (NCHUNK + CH - 1) / CH;       // 782
    hp_fused<<<nblk, 256, 0, stream>>>(x, w1f, w2f, b1, b2, batch, s, out);
}